// Round 1
// baseline (446.250 us; speedup 1.0000x reference)
//
#include <hip/hip_runtime.h>
#include <math.h>

// Problem constants
#define BB     512
#define INF    256
#define CONDF  128
#define NEXP   8
#define HDIM   64
#define DPP    64
#define DNN    128
#define TPE    49280      // IN*DP + IN*DN + DN
#define TOTC   394240     // N*TPE
#define SEC_WN 16384      // IN*DP
#define SEC_BN 49152      // IN*DP + IN*DN
#define NSPLIT 4
#define CW     1536       // global GEMM columns: 8 experts * (64 wp + 128 wn)

// Workspace layout (bytes)
#define XH_OFF   0x0u        // ushort [512][320]  = 327680 B  (x bf16 | h bf16)
#define BEXT_OFF 0x50000u    // ushort [1536][320] = 983040 B  (K-tail B, k-contiguous per col)
#define GW_OFF   0x140000u   // float  [512][8]
#define CB_OFF   0x144000u   // float  [1536]      (per-column bias for wn cols)
#define P_OFF    0x146000u   // float  [4][512][1536] partials = 12.6 MB

typedef __bf16          bf16x8 __attribute__((ext_vector_type(8)));
typedef unsigned short  us8    __attribute__((ext_vector_type(8)));
typedef float           f32x4  __attribute__((ext_vector_type(4)));

__device__ __forceinline__ unsigned short f2bf(float f) {
  unsigned u = __builtin_bit_cast(unsigned, f);
  u += 0x7fffu + ((u >> 16) & 1u);           // round-to-nearest-even
  return (unsigned short)(u >> 16);
}
__device__ __forceinline__ float bf2f(unsigned short u) {
  return __builtin_bit_cast(float, ((unsigned)u) << 16);
}

// ---------------- K1: per-sample prep: h = relu(cond@hW1+hb1), gw = softmax, xh = [bf16(x)|bf16(h)]
__global__ void k_prep(const float* __restrict__ x, const float* __restrict__ cond,
                       const float* __restrict__ hW1, const float* __restrict__ hb1,
                       const float* __restrict__ gW1, const float* __restrict__ gb1,
                       const float* __restrict__ gW2, const float* __restrict__ gb2,
                       unsigned short* __restrict__ xh, float* __restrict__ gw) {
  const int b = blockIdx.x;
  const int tid = threadIdx.x;          // 128 threads
  __shared__ float cond_s[CONDF];
  __shared__ float g1_s[24];
  __shared__ float l_s[8];
  __shared__ float e_s[8];
  cond_s[tid] = cond[b * CONDF + tid];
  __syncthreads();
  if (tid < HDIM) {
    float acc = hb1[tid];
    for (int q = 0; q < CONDF; ++q) acc = fmaf(cond_s[q], hW1[q * HDIM + tid], acc);
    acc = fmaxf(acc, 0.f);
    xh[b * 320 + 256 + tid] = f2bf(acc);
  }
  xh[b * 320 + tid]       = f2bf(x[b * INF + tid]);
  xh[b * 320 + 128 + tid] = f2bf(x[b * INF + 128 + tid]);
  if (tid < 24) {
    float acc = gb1[tid];
    for (int q = 0; q < CONDF; ++q) acc = fmaf(cond_s[q], gW1[q * 24 + tid], acc);
    g1_s[tid] = fmaxf(acc, 0.f);
  }
  __syncthreads();
  if (tid < NEXP) {
    float acc = gb2[tid];
    for (int j = 0; j < 24; ++j) acc = fmaf(g1_s[j], gW2[j * NEXP + tid], acc);
    l_s[tid] = acc;
  }
  __syncthreads();
  if (tid < NEXP) {
    float m = l_s[0];
    for (int j = 1; j < NEXP; ++j) m = fmaxf(m, l_s[j]);
    e_s[tid] = expf(l_s[tid] - m);
  }
  __syncthreads();
  if (tid < NEXP) {
    float s = 0.f;
    for (int j = 0; j < NEXP; ++j) s += e_s[j];
    gw[b * NEXP + tid] = e_s[tid] / s;
  }
}

// ---------------- K2: K-tail B matrix (k-contiguous per column) + per-column bias
// global col c = ne*192 + r;  r<64 -> wp p=r ;  r>=64 -> wn j=r-64
__global__ void k_bext(const float* __restrict__ bwp, const float* __restrict__ bwn,
                       const float* __restrict__ bbn, const float* __restrict__ hW2,
                       const float* __restrict__ hb2,
                       unsigned short* __restrict__ BextT, float* __restrict__ colbias) {
  const int c = blockIdx.x;     // 0..1535
  const int tid = threadIdx.x;  // 64
  const int ne = c / 192, r = c - ne * 192;
  for (int k = tid; k < 320; k += 64) {
    float v;
    if (k < 256) {
      const int i = k;
      if (r < 64) v = bwp[(ne * INF + i) * DPP + r] + hb2[(size_t)ne * TPE + i * DPP + r];
      else        v = bwn[(ne * INF + i) * DNN + (r - 64)] + hb2[(size_t)ne * TPE + SEC_WN + i * DNN + (r - 64)];
    } else {
      const int t = k - 256;
      v = (r < 64) ? 0.f : hW2[(size_t)t * TOTC + (size_t)ne * TPE + SEC_BN + (r - 64)];
    }
    BextT[(size_t)c * 320 + k] = f2bf(v);
  }
  if (tid == 0)
    colbias[c] = (r < 64) ? 0.f
               : bbn[ne * DNN + (r - 64)] + hb2[(size_t)ne * TPE + SEC_BN + (r - 64)];
}

// ---------------- K3: split-K MFMA GEMM.  P[s][b][c] partial over t in [16s,16s+16).
// Block tile 128m x 64n, 4 waves each 32m x 64n, K-step = 64 (one t, 64 i).
// A built on the fly: A[b][t*256+i] = bf16(h_b,t * x_b,i). B transposed to LDS [n][k].
template <int DST>   // section row stride in hW2: 64 for wp cols, 128 for wn cols
__launch_bounds__(256)
__global__ void k_gemm(const float* __restrict__ hW2,
                       const unsigned short* __restrict__ xh,
                       const unsigned short* __restrict__ BextT,
                       float* __restrict__ P) {
  const int ctx = blockIdx.x;
  const int mt  = blockIdx.y;
  const int s   = blockIdx.z;
  int ne, c0g; size_t secoff;
  if (DST == 64) { ne = ctx; secoff = (size_t)ne * TPE; c0g = ne * 192; }
  else { ne = ctx >> 1; const int half = ctx & 1;
         secoff = (size_t)ne * TPE + SEC_WN + half * 64; c0g = ne * 192 + 64 + half * 64; }
  const int mbase = mt * 128;
  const int tid = threadIdx.x;

  // stride 72 (= 36 dwords) rotates banks by 4/row -> b128 ops at the 8-cycle floor
  __shared__ __align__(16) unsigned short Alds[128 * 72];
  __shared__ __align__(16) unsigned short Blds[64 * 72];

  f32x4 acc[2][4];
#pragma unroll
  for (int mi = 0; mi < 2; ++mi)
#pragma unroll
    for (int ni = 0; ni < 4; ++ni) acc[mi][ni] = (f32x4){0.f, 0.f, 0.f, 0.f};

  const int arow0 = tid >> 3;   // 0..31
  const int akg   = tid & 7;    // 0..7
  const int bn    = tid & 63;   // B-stage column lane
  const int bkh   = tid >> 6;   // 0..3
  const int wv    = tid >> 6;   // wave id
  const int lane  = tid & 63;
  const int lrow  = lane & 15;
  const int quad  = lane >> 4;

  auto step_compute = [&]() {
    __syncthreads();
#pragma unroll
    for (int kh = 0; kh < 2; ++kh) {
      const int ko = kh * 32 + quad * 8;
      bf16x8 a[2], bf[4];
#pragma unroll
      for (int mi = 0; mi < 2; ++mi)
        a[mi] = *(const bf16x8*)(&Alds[(wv * 32 + mi * 16 + lrow) * 72 + ko]);
#pragma unroll
      for (int ni = 0; ni < 4; ++ni)
        bf[ni] = *(const bf16x8*)(&Blds[(ni * 16 + lrow) * 72 + ko]);
#pragma unroll
      for (int mi = 0; mi < 2; ++mi)
#pragma unroll
        for (int ni = 0; ni < 4; ++ni)
          acc[mi][ni] = __builtin_amdgcn_mfma_f32_16x16x32_bf16(a[mi], bf[ni], acc[mi][ni], 0, 0, 0);
    }
    __syncthreads();
  };

  for (int t = s * 16; t < (s + 1) * 16; ++t) {
#pragma unroll
    for (int ib = 0; ib < 4; ++ib) {
      // stage A: z = h*x, bf16
#pragma unroll
      for (int rr = 0; rr < 4; ++rr) {
        const int row = arow0 + rr * 32;
        const int brow = mbase + row;
        const float hv = bf2f(xh[brow * 320 + 256 + t]);
        us8 xv = *(const us8*)(xh + brow * 320 + ib * 64 + akg * 8);
        us8 o;
#pragma unroll
        for (int j = 0; j < 8; ++j) o[j] = f2bf(hv * bf2f(xv[j]));
        *(us8*)(&Alds[row * 72 + akg * 8]) = o;
      }
      // stage B: transpose 64k x 64n region of hW2 into LDS [n][k], fp32->bf16
      {
        const float* wb = hW2 + (size_t)t * TOTC + secoff + (size_t)(ib * 64) * DST + bn;
#pragma unroll
        for (int kk2 = 0; kk2 < 2; ++kk2) {
          const int kk = bkh + kk2 * 4;
          const float* p = wb + (size_t)kk * 8 * DST;
          us8 o;
#pragma unroll
          for (int j = 0; j < 8; ++j) o[j] = f2bf(p[j * DST]);
          *(us8*)(&Blds[bn * 72 + kk * 8]) = o;
        }
      }
      step_compute();
    }
  }

  // K-tail (base weights + hb2 + bias-col rows), done once (split 0)
  if (s == 0) {
#pragma unroll
    for (int kb = 0; kb < 5; ++kb) {
#pragma unroll
      for (int rr = 0; rr < 4; ++rr) {
        const int row = arow0 + rr * 32;
        const int brow = mbase + row;
        us8 v = *(const us8*)(xh + brow * 320 + kb * 64 + akg * 8);
        *(us8*)(&Alds[row * 72 + akg * 8]) = v;
      }
#pragma unroll
      for (int kk2 = 0; kk2 < 2; ++kk2) {
        const int kk = bkh + kk2 * 4;
        us8 v = *(const us8*)(BextT + (size_t)(c0g + bn) * 320 + kb * 64 + kk * 8);
        *(us8*)(&Blds[bn * 72 + kk * 8]) = v;
      }
      step_compute();
    }
  }

  // write partial tile: D row = quad*4+reg, col = lane&15
#pragma unroll
  for (int mi = 0; mi < 2; ++mi)
#pragma unroll
    for (int ni = 0; ni < 4; ++ni) {
      const int bb0 = mbase + wv * 32 + mi * 16 + quad * 4;
      const int cc  = c0g + ni * 16 + lrow;
      float* pp = P + ((size_t)s * BB + bb0) * CW + cc;
#pragma unroll
      for (int r = 0; r < 4; ++r) pp[(size_t)r * CW] = acc[mi][ni][r];
    }
}

// ---------------- K4: epilogue — sum split-K partials, cos/sin/relu, softmax-gated expert sum
__global__ void k_epi(const float* __restrict__ P, const float* __restrict__ gw,
                      const float* __restrict__ colbias, float* __restrict__ out) {
  const int b = blockIdx.x;
  const int r = threadIdx.x;      // 192: wave0 = wp cols, waves1-2 = wn cols (uniform branches)
  __shared__ float gws[NEXP];
  if (r < NEXP) gws[r] = gw[b * NEXP + r];
  __syncthreads();
  float co = 0.f, si = 0.f, nc = 0.f;
  for (int n = 0; n < NEXP; ++n) {
    const int c = n * 192 + r;
    float v = colbias[c];
#pragma unroll
    for (int s2 = 0; s2 < NSPLIT; ++s2) v += P[((size_t)s2 * BB + b) * CW + c];
    const float g = gws[n];
    if (r < 64) { co = fmaf(g, cosf(v), co); si = fmaf(g, sinf(v), si); }
    else        { nc = fmaf(g, fmaxf(v, 0.f), nc); }
  }
  if (r < 64) { out[b * 256 + r] = co; out[b * 256 + 64 + r] = si; }
  else        { out[b * 256 + 128 + (r - 64)] = nc; }
}

extern "C" void kernel_launch(void* const* d_in, const int* in_sizes, int n_in,
                              void* d_out, int out_size, void* d_ws, size_t ws_size,
                              hipStream_t stream) {
  const float* x    = (const float*)d_in[0];
  const float* cond = (const float*)d_in[1];
  const float* bwp  = (const float*)d_in[2];
  const float* bwn  = (const float*)d_in[3];
  const float* bbn  = (const float*)d_in[4];
  const float* hW1  = (const float*)d_in[5];
  const float* hb1  = (const float*)d_in[6];
  const float* hW2  = (const float*)d_in[7];
  const float* hb2  = (const float*)d_in[8];
  const float* gW1  = (const float*)d_in[9];
  const float* gb1  = (const float*)d_in[10];
  const float* gW2  = (const float*)d_in[11];
  const float* gb2  = (const float*)d_in[12];
  float* out = (float*)d_out;
  char* ws = (char*)d_ws;

  unsigned short* xh    = (unsigned short*)(ws + XH_OFF);
  unsigned short* BextT = (unsigned short*)(ws + BEXT_OFF);
  float* gw      = (float*)(ws + GW_OFF);
  float* colbias = (float*)(ws + CB_OFF);
  float* Pp      = (float*)(ws + P_OFF);

  hipLaunchKernelGGL(k_prep, dim3(BB), dim3(128), 0, stream,
                     x, cond, hW1, hb1, gW1, gb1, gW2, gb2, xh, gw);
  hipLaunchKernelGGL(k_bext, dim3(CW), dim3(64), 0, stream,
                     bwp, bwn, bbn, hW2, hb2, BextT, colbias);
  hipLaunchKernelGGL((k_gemm<64>),  dim3(8, 4, NSPLIT),  dim3(256), 0, stream, hW2, xh, BextT, Pp);
  hipLaunchKernelGGL((k_gemm<128>), dim3(16, 4, NSPLIT), dim3(256), 0, stream, hW2, xh, BextT, Pp);
  hipLaunchKernelGGL(k_epi, dim3(BB), dim3(192), 0, stream, Pp, gw, colbias, out);
}

// Round 2
// 254.231 us; speedup vs baseline: 1.7553x; 1.7553x over previous
//
#include <hip/hip_runtime.h>
#include <math.h>

// Problem constants
#define BB     512
#define INF    256
#define CONDF  128
#define NEXP   8
#define HDIM   64
#define TPE    49280      // IN*DP + IN*DN + DN
#define TOTC   394240     // N*TPE
#define NSPLIT 8
#define CW     1536       // GEMM columns: 8 experts * (64 wp + 128 wn)
#define KB     261        // K blocks of 64: 64*4 main + 5 tail (16704 total K)

// Workspace layout (bytes). Total ~93.6 MB.
#define AZ_OFF 0u                     // ushort [261][512][64]  = 17,104,896
#define BT_OFF 17104896u              // ushort [261][1536][64] = 51,314,688
#define P_OFF  68419584u              // float  [8][512][1536]  = 25,165,824
#define GW_OFF 93585408u              // float  [512][8]
#define CB_OFF 93601792u              // float  [1536]

typedef __bf16          bf16x8 __attribute__((ext_vector_type(8)));
typedef unsigned short  us8    __attribute__((ext_vector_type(8)));
typedef float           f32x4  __attribute__((ext_vector_type(4)));

__device__ __forceinline__ unsigned short f2bf(float f) {
  unsigned u = __builtin_bit_cast(unsigned, f);
  u += 0x7fffu + ((u >> 16) & 1u);           // RNE
  return (unsigned short)(u >> 16);
}

__device__ __forceinline__ void gld16(const void* g, const void* l) {
  __builtin_amdgcn_global_load_lds(
      (const __attribute__((address_space(1))) unsigned int*)g,
      (__attribute__((address_space(3))) unsigned int*)l, 16, 0, 0);
}

// ---------------- K1: h = relu(cond@hW1+hb1), gw = softmax gates, Az = bf16 A matrix
// Az[kb][b][ko], k = t*256+i for k<16384 -> z = h_t*x_i ; tail k=16384+j -> x_j | h_(j-256)
__global__ void k_prep(const float* __restrict__ x, const float* __restrict__ cond,
                       const float* __restrict__ hW1, const float* __restrict__ hb1,
                       const float* __restrict__ gW1, const float* __restrict__ gb1,
                       const float* __restrict__ gW2, const float* __restrict__ gb2,
                       unsigned short* __restrict__ Az, float* __restrict__ gw) {
  const int b = blockIdx.x;
  const int tid = threadIdx.x;          // 256
  __shared__ float xs[INF], cs[CONDF], hs[HDIM], g1[24], ls[8], es[8];
  xs[tid] = x[b * INF + tid];
  if (tid < CONDF) cs[tid] = cond[b * CONDF + tid];
  __syncthreads();
  if (tid < HDIM) {
    float acc = hb1[tid];
    for (int q = 0; q < CONDF; ++q) acc = fmaf(cs[q], hW1[q * HDIM + tid], acc);
    hs[tid] = fmaxf(acc, 0.f);
  }
  if (tid >= 64 && tid < 88) {
    const int r = tid - 64;
    float acc = gb1[r];
    for (int q = 0; q < CONDF; ++q) acc = fmaf(cs[q], gW1[q * 24 + r], acc);
    g1[r] = fmaxf(acc, 0.f);
  }
  __syncthreads();
  if (tid < NEXP) {
    float acc = gb2[tid];
    for (int j = 0; j < 24; ++j) acc = fmaf(g1[j], gW2[j * NEXP + tid], acc);
    ls[tid] = acc;
  }
  __syncthreads();
  if (tid < NEXP) {
    float m = ls[0];
    for (int j = 1; j < NEXP; ++j) m = fmaxf(m, ls[j]);
    es[tid] = expf(ls[tid] - m);
  }
  __syncthreads();
  if (tid < NEXP) {
    float s = 0.f;
    for (int j = 0; j < NEXP; ++j) s += es[j];
    gw[b * NEXP + tid] = es[tid] / s;
  }
  // z writes: 8 t-groups x 32 i-octets
  const int t0 = tid >> 5, ig = tid & 31;
#pragma unroll
  for (int tt = 0; tt < 8; ++tt) {
    const int t = tt * 8 + t0;
    const float hv = hs[t];
    us8 o;
#pragma unroll
    for (int j = 0; j < 8; ++j) o[j] = f2bf(hv * xs[ig * 8 + j]);
    *(us8*)(Az + ((size_t)(t * 4 + (ig >> 3)) * BB + b) * 64 + (ig & 7) * 8) = o;
  }
  // tail rows: kb 256..259 = x, kb 260 = h
  Az[((size_t)(256 + (tid >> 6)) * BB + b) * 64 + (tid & 63)] = f2bf(xs[tid]);
  if (tid < HDIM) Az[((size_t)260 * BB + b) * 64 + tid] = f2bf(hs[tid]);
}

// ---------------- K2: Bt main part. Bt[kb][c][ko] bf16, kb = t*4+ib, c = ne*192+r.
// One block per (t, ne, sec) where sec 0 = wp(64 cols), 1/2 = wn halves.
__global__ void k_bt(const float* __restrict__ hW2, unsigned short* __restrict__ Bt) {
  const int bx = blockIdx.x;            // 64*8*3 = 1536
  const int t = bx / 24, rem = bx % 24, ne = rem / 3, sec = rem % 3;
  const size_t base = (size_t)t * TOTC + (size_t)ne * TPE + (sec ? 16384 : 0);
  const int dst  = sec ? 128 : 64;
  const int poff = (sec == 2) ? 64 : 0;
  const int cbase = ne * 192 + (sec == 0 ? 0 : (sec == 1 ? 64 : 128));
  const int tid = threadIdx.x;          // 256
  __shared__ unsigned short Ls[64 * 272];   // [p][i], pad 272 (row = 544 B, 16B-aligned)
#pragma unroll
  for (int it = 0; it < 16; ++it) {
    const int f = it * 256 + tid;       // 4096 float4s
    const int i = f >> 4, p4 = (f & 15) * 4;
    f32x4 v = *(const f32x4*)(hW2 + base + (size_t)i * dst + poff + p4);
#pragma unroll
    for (int j = 0; j < 4; ++j) Ls[(p4 + j) * 272 + i] = f2bf(v[j]);
  }
  __syncthreads();
#pragma unroll
  for (int it2 = 0; it2 < 8; ++it2) {
    const int of = it2 * 256 + tid;     // 2048 us8 outputs
    const int p = of >> 5, seg = of & 31, ib = seg >> 3, k8 = seg & 7;
    us8 o = *(const us8*)(&Ls[p * 272 + ib * 64 + k8 * 8]);
    *(us8*)(Bt + ((size_t)(t * 4 + ib) * CW + cbase + p) * 64 + k8 * 8) = o;
  }
}

// ---------------- K2b: Bt tail rows (base weights + hb2 folds + bias-delta rows) + colbias
__global__ void k_btail(const float* __restrict__ bwp, const float* __restrict__ bwn,
                        const float* __restrict__ bbn, const float* __restrict__ hW2,
                        const float* __restrict__ hb2,
                        unsigned short* __restrict__ Bt, float* __restrict__ colbias) {
  const int c = blockIdx.x;             // 1536
  const int tid = threadIdx.x;          // 64
  const int ne = c / 192, r = c % 192;
#pragma unroll
  for (int kb = 0; kb < 5; ++kb) {
    const int j = kb * 64 + tid;        // 0..320
    float v;
    if (j < 256) {
      const int i = j;
      if (r < 64) v = bwp[(ne * INF + i) * 64 + r] + hb2[(size_t)ne * TPE + i * 64 + r];
      else        v = bwn[(ne * INF + i) * 128 + (r - 64)] + hb2[(size_t)ne * TPE + 16384 + i * 128 + (r - 64)];
    } else {
      const int t = j - 256;
      v = (r < 64) ? 0.f : hW2[(size_t)t * TOTC + (size_t)ne * TPE + 49152 + (r - 64)];
    }
    Bt[((size_t)(256 + kb) * CW + c) * 64 + tid] = f2bf(v);
  }
  if (tid == 0)
    colbias[c] = (r < 64) ? 0.f
               : bbn[ne * 128 + (r - 64)] + hb2[(size_t)ne * TPE + 49152 + (r - 64)];
}

// ---------------- K3: split-K MFMA GEMM. Block 128m x 128n, 4 waves (2x2) of 64x64.
// A/B staged via global_load_lds w16 into XOR-swizzled LDS; ds_read_b128 frags.
__launch_bounds__(256)
__global__ void k_gemm(const unsigned short* __restrict__ Az,
                       const unsigned short* __restrict__ Bt,
                       float* __restrict__ P) {
  const int nt = blockIdx.x;            // 12
  const int mt = blockIdx.y;            // 4
  const int s  = blockIdx.z;            // 8
  const int m0 = mt * 128, n0 = nt * 128;
  const int kb0 = s * 33;
  const int kb1 = (kb0 + 33 < KB) ? kb0 + 33 : KB;
  const int tid = threadIdx.x;
  __shared__ __align__(16) unsigned short As[128 * 64];
  __shared__ __align__(16) unsigned short Bs[128 * 64];

  f32x4 acc[4][4];
#pragma unroll
  for (int mi = 0; mi < 4; ++mi)
#pragma unroll
    for (int ni = 0; ni < 4; ++ni) acc[mi][ni] = (f32x4){0.f, 0.f, 0.f, 0.f};

  const int wv = tid >> 6, lane = tid & 63;
  const int wm = wv >> 1, wn = wv & 1;
  const int lrow = lane & 15, quad = lane >> 4;
  // staging geometry: issue it covers rows it*32..+32; src granule = (tid&7) ^ (row&7)
  const int srow = tid >> 3;
  const int sg0  = tid & 7;

  for (int kb = kb0; kb < kb1; ++kb) {
    const unsigned short* ab = Az + ((size_t)kb * BB + m0) * 64;
    const unsigned short* bb = Bt + ((size_t)kb * CW + n0) * 64;
#pragma unroll
    for (int it = 0; it < 4; ++it) {
      const int r = it * 32 + srow;
      const int g = sg0 ^ (r & 7);
      const int ldsoff = __builtin_amdgcn_readfirstlane(it * 4096 + wv * 1024);
      gld16(ab + (size_t)r * 64 + g * 8, (const char*)As + ldsoff);
      gld16(bb + (size_t)r * 64 + g * 8, (const char*)Bs + ldsoff);
    }
    __syncthreads();
#pragma unroll
    for (int kh = 0; kh < 2; ++kh) {
      bf16x8 af[4], bfr[4];
#pragma unroll
      for (int mi = 0; mi < 4; ++mi) {
        const int r = wm * 64 + mi * 16 + lrow;
        const int g = (kh * 4 + quad) ^ (r & 7);
        af[mi] = *(const bf16x8*)(As + r * 64 + g * 8);
      }
#pragma unroll
      for (int ni = 0; ni < 4; ++ni) {
        const int r = wn * 64 + ni * 16 + lrow;
        const int g = (kh * 4 + quad) ^ (r & 7);
        bfr[ni] = *(const bf16x8*)(Bs + r * 64 + g * 8);
      }
#pragma unroll
      for (int mi = 0; mi < 4; ++mi)
#pragma unroll
        for (int ni = 0; ni < 4; ++ni)
          acc[mi][ni] = __builtin_amdgcn_mfma_f32_16x16x32_bf16(af[mi], bfr[ni], acc[mi][ni], 0, 0, 0);
    }
    __syncthreads();
  }

  // write partials: D row = quad*4+reg, col = lane&15
#pragma unroll
  for (int mi = 0; mi < 4; ++mi) {
    const int row0 = m0 + wm * 64 + mi * 16 + quad * 4;
#pragma unroll
    for (int ni = 0; ni < 4; ++ni) {
      const int col = n0 + wn * 64 + ni * 16 + lrow;
      float* pp = P + ((size_t)s * BB + row0) * CW + col;
#pragma unroll
      for (int r = 0; r < 4; ++r) pp[(size_t)r * CW] = acc[mi][ni][r];
    }
  }
}

// ---------------- K4: epilogue — sum split-K partials, cos/sin/relu, softmax-gated expert sum
__global__ void k_epi(const float* __restrict__ P, const float* __restrict__ gw,
                      const float* __restrict__ colbias, float* __restrict__ out) {
  const int b = blockIdx.x;
  const int r = threadIdx.x;            // 192: wave0 = wp cols, waves1-2 = wn cols
  __shared__ float gws[NEXP];
  if (r < NEXP) gws[r] = gw[b * NEXP + r];
  __syncthreads();
  float co = 0.f, si = 0.f, nc = 0.f;
  for (int n = 0; n < NEXP; ++n) {
    const int c = n * 192 + r;
    float v = colbias[c];
#pragma unroll
    for (int s2 = 0; s2 < NSPLIT; ++s2) v += P[((size_t)s2 * BB + b) * CW + c];
    const float g = gws[n];
    if (r < 64) { co = fmaf(g, cosf(v), co); si = fmaf(g, sinf(v), si); }
    else        { nc = fmaf(g, fmaxf(v, 0.f), nc); }
  }
  if (r < 64) { out[b * 256 + r] = co; out[b * 256 + 64 + r] = si; }
  else        { out[b * 256 + 128 + (r - 64)] = nc; }
}

extern "C" void kernel_launch(void* const* d_in, const int* in_sizes, int n_in,
                              void* d_out, int out_size, void* d_ws, size_t ws_size,
                              hipStream_t stream) {
  const float* x    = (const float*)d_in[0];
  const float* cond = (const float*)d_in[1];
  const float* bwp  = (const float*)d_in[2];
  const float* bwn  = (const float*)d_in[3];
  const float* bbn  = (const float*)d_in[4];
  const float* hW1  = (const float*)d_in[5];
  const float* hb1  = (const float*)d_in[6];
  const float* hW2  = (const float*)d_in[7];
  const float* hb2  = (const float*)d_in[8];
  const float* gW1  = (const float*)d_in[9];
  const float* gb1  = (const float*)d_in[10];
  const float* gW2  = (const float*)d_in[11];
  const float* gb2  = (const float*)d_in[12];
  float* out = (float*)d_out;
  char* ws = (char*)d_ws;

  unsigned short* Az = (unsigned short*)(ws + AZ_OFF);
  unsigned short* Bt = (unsigned short*)(ws + BT_OFF);
  float* Pp      = (float*)(ws + P_OFF);
  float* gw      = (float*)(ws + GW_OFF);
  float* colbias = (float*)(ws + CB_OFF);

  hipLaunchKernelGGL(k_prep, dim3(BB), dim3(256), 0, stream,
                     x, cond, hW1, hb1, gW1, gb1, gW2, gb2, Az, gw);
  hipLaunchKernelGGL(k_bt, dim3(1536), dim3(256), 0, stream, hW2, Bt);
  hipLaunchKernelGGL(k_btail, dim3(CW), dim3(64), 0, stream,
                     bwp, bwn, bbn, hW2, hb2, Bt, colbias);
  hipLaunchKernelGGL(k_gemm, dim3(12, 4, NSPLIT), dim3(256), 0, stream, Az, Bt, Pp);
  hipLaunchKernelGGL(k_epi, dim3(BB), dim3(192), 0, stream, Pp, gw, colbias, out);
}